// Round 1
// baseline (72.298 us; speedup 1.0000x reference)
//
#include <hip/hip_runtime.h>

// Problem: N=4096 rows, F=256 features, H=4 heads.
// Key algebraic identity: softmax_j(s_i[i,h] + s_j[j,h] + b[h]) == softmax_j(s_j[j,h])
// (i- and h-constant terms cancel), so attention weights are independent of i and
// the output is ONE length-F vector broadcast to all N rows:
//   v[f] = (1/H) * sum_h ( sum_j exp(s_j[j,h]) * x[j,f] ) / ( sum_j exp(s_j[j,h]) )
//   out[i,f] = leaky_relu(v[f], 0.2)   for all i.

#define NROWS 4096
#define FDIM  256
#define HHEADS 4
#define ROWS_PER_BLK 64
#define PAD 260   // 260*4B = 1040B: 16B-aligned rows, banks (4r+c)%32 -> <=2-way conflict (free)

// ws layout: u[H*F] floats, then Z[H] floats. Zeroed by hipMemsetAsync each call.

__global__ __launch_bounds__(256) void k1_scores(const float* __restrict__ x,
                                                 const float* __restrict__ W,
                                                 float* __restrict__ u,
                                                 float* __restrict__ Z) {
    __shared__ float x_lds[ROWS_PER_BLK * PAD];
    __shared__ float w_lds[FDIM * HHEADS];        // w_lds[c*4+h] = W2[h][c]
    __shared__ float e_lds[ROWS_PER_BLK * HHEADS];

    const int t = threadIdx.x;
    const int row0 = blockIdx.x * ROWS_PER_BLK;

    // Stage W2 (= W[:, F:2F], W row stride 2F=512) into LDS, interleaved by head.
    for (int i = t; i < FDIM * HHEADS; i += 256) {
        int h = i >> 8, c = i & 255;
        w_lds[c * 4 + h] = W[h * (2 * FDIM) + FDIM + c];
    }
    // Stage this block's 64 x-rows into LDS with coalesced float4 loads.
    for (int i = t; i < ROWS_PER_BLK * (FDIM / 4); i += 256) {
        int r = i >> 6, c4 = i & 63;
        float4 v = ((const float4*)x)[(size_t)(row0 + r) * (FDIM / 4) + c4];
        *(float4*)&x_lds[r * PAD + c4 * 4] = v;
    }
    __syncthreads();

    // Phase 1: one (row, head) dot product per thread -> e = exp(s).
    {
        int r = t >> 2, h = t & 3;
        const float* xr = &x_lds[r * PAD];
        float acc = 0.f;
        #pragma unroll 8
        for (int c = 0; c < FDIM; ++c)
            acc = fmaf(xr[c], w_lds[c * 4 + h], acc);
        e_lds[r * 4 + h] = __expf(acc);   // |s| < ~3: no max-shift needed in fp32
    }
    __syncthreads();

    // Per-block softmax-denominator partials.
    if (t < HHEADS) {
        float z = 0.f;
        for (int r = 0; r < ROWS_PER_BLK; ++r) z += e_lds[r * 4 + t];
        atomicAdd(&Z[t], z);
    }

    // Phase 2: per-block partial of u[h][f] = sum_j e[h,j]*x[j,f];  f = t.
    float a0 = 0.f, a1 = 0.f, a2 = 0.f, a3 = 0.f;
    for (int r = 0; r < ROWS_PER_BLK; ++r) {
        float xv = x_lds[r * PAD + t];
        float4 e4 = *(const float4*)&e_lds[r * 4];
        a0 = fmaf(e4.x, xv, a0);
        a1 = fmaf(e4.y, xv, a1);
        a2 = fmaf(e4.z, xv, a2);
        a3 = fmaf(e4.w, xv, a3);
    }
    atomicAdd(&u[0 * FDIM + t], a0);
    atomicAdd(&u[1 * FDIM + t], a1);
    atomicAdd(&u[2 * FDIM + t], a2);
    atomicAdd(&u[3 * FDIM + t], a3);
}

// K2: finalize v[f], apply leaky_relu, broadcast-write 8 rows per block (512 blocks).
__global__ __launch_bounds__(256) void k2_out(const float* __restrict__ u,
                                              const float* __restrict__ Z,
                                              float* __restrict__ out) {
    __shared__ float v_lds[FDIM];
    const int t = threadIdx.x;
    {
        float z0 = Z[0], z1 = Z[1], z2 = Z[2], z3 = Z[3];
        float val = 0.25f * (u[t] / z0 + u[FDIM + t] / z1 +
                             u[2 * FDIM + t] / z2 + u[3 * FDIM + t] / z3);
        v_lds[t] = val > 0.f ? val : 0.2f * val;
    }
    __syncthreads();

    const int row0 = blockIdx.x * 8;
    const int c4 = t & 63;          // float4 column 0..63
    const int sub = t >> 6;         // 0..3
    float4 val4 = *(const float4*)&v_lds[c4 * 4];
    float4* out4 = (float4*)out;
    out4[(size_t)(row0 + sub) * (FDIM / 4) + c4] = val4;
    out4[(size_t)(row0 + sub + 4) * (FDIM / 4) + c4] = val4;
}

extern "C" void kernel_launch(void* const* d_in, const int* in_sizes, int n_in,
                              void* d_out, int out_size, void* d_ws, size_t ws_size,
                              hipStream_t stream) {
    const float* x = (const float*)d_in[0];   // (4096, 256)
    const float* W = (const float*)d_in[1];   // (4, 512)
    // d_in[2] = b is unused: it cancels in the softmax.
    float* u = (float*)d_ws;                  // H*F = 1024 floats
    float* Z = u + HHEADS * FDIM;             // H   = 4 floats
    float* out = (float*)d_out;

    hipMemsetAsync(d_ws, 0, (HHEADS * FDIM + HHEADS) * sizeof(float), stream);
    k1_scores<<<NROWS / ROWS_PER_BLK, 256, 0, stream>>>(x, W, u, Z);
    k2_out<<<NROWS / 8, 256, 0, stream>>>(u, Z, out);
}